// Round 11
// baseline (569.961 us; speedup 1.0000x reference)
//
#include <hip/hip_runtime.h>
#include <math.h>

#define BIGI (1 << 30)

// ---- workspace layout (4-byte words), total 176128 words = 688 KB ----
#define PM_OFF    0         // 2048 x int4 minmax partials
#define HT0_OFF   8192      // 4 x 16 x 256 tagged u64 (h1 history)
#define HT2_OFF   40960     // 4 x 2 x 256 tagged u64 (h2 double buffer)
#define XG1_OFF   45056     // 4 x 16 x 1024 tagged u64 (xg1 per t)
#define ZERO_BEG  8192
#define ZERO_END  176128

// ---- output layout (floats) ----
#define OUT_DELTAS 0       // (4,5,4)
#define OUT_PBB    80      // (4,5,4)
#define OUT_LOC    160     // (4,5,2)
#define OUT_SCL    200     // (4,5,2)
#define OUT_MF     240     // (4,16,256)
#define OUT_CONF   16624   // (4,5)
#define OUT_BBOX   16644   // (4,16,4)

__device__ __forceinline__ float sigmoidf_(float x) { return 1.0f / (1.0f + expf(-x)); }

// ---- self-signaling exchange: one 8B atomic payload = (tag<<32)|float ----
__device__ __forceinline__ void storeh(unsigned long long* p, float h, int tag) {
    unsigned long long v =
        ((unsigned long long)(unsigned)tag << 32) | (unsigned long long)__float_as_uint(h);
    __hip_atomic_store(p, v, __ATOMIC_RELAXED, __HIP_MEMORY_SCOPE_AGENT);
}
__device__ __forceinline__ float pollh(const unsigned long long* p, int tag) {
    unsigned long long v = __hip_atomic_load(p, __ATOMIC_RELAXED, __HIP_MEMORY_SCOPE_AGENT);
    while ((int)(v >> 32) != tag) {
        __builtin_amdgcn_s_sleep(1);
        v = __hip_atomic_load(p, __ATOMIC_RELAXED, __HIP_MEMORY_SCOPE_AGENT);
    }
    return __uint_as_float((unsigned)v);
}
// dual poll: both loads issued before spinning (one serial detect latency)
__device__ __forceinline__ float2 pollh2(const unsigned long long* p1, int tag1,
                                         const unsigned long long* p2, int tag2) {
    unsigned long long v1 = __hip_atomic_load(p1, __ATOMIC_RELAXED, __HIP_MEMORY_SCOPE_AGENT);
    unsigned long long v2 = __hip_atomic_load(p2, __ATOMIC_RELAXED, __HIP_MEMORY_SCOPE_AGENT);
    while ((int)(v1 >> 32) != tag1) {
        __builtin_amdgcn_s_sleep(1);
        v1 = __hip_atomic_load(p1, __ATOMIC_RELAXED, __HIP_MEMORY_SCOPE_AGENT);
    }
    while ((int)(v2 >> 32) != tag2) {
        __builtin_amdgcn_s_sleep(1);
        v2 = __hip_atomic_load(p2, __ATOMIC_RELAXED, __HIP_MEMORY_SCOPE_AGENT);
    }
    return make_float2(__uint_as_float((unsigned)v1), __uint_as_float((unsigned)v2));
}

// ---------------- kernel 1: minmax partials + zero tag region ----------------
__global__ __launch_bounds__(256) void k_minmax(const float4* __restrict__ pred,
                                                int* __restrict__ ws) {
    int tid = threadIdx.x;
    {   // zero tagged regions (2048 blocks cover the range in one pass)
        int i = ZERO_BEG + blockIdx.x * 256 + tid;
        if (i < ZERO_END) ws[i] = 0;
    }
    int img = blockIdx.x >> 5;
    int chunk = blockIdx.x & 31;
    int base = img * 262144 + chunk * 8192 + tid;
    int xmn = BIGI, xmx = -1, ymn = BIGI, ymx = -1;
#pragma unroll 4
    for (int i = 0; i < 32; ++i) {
        int idx4 = base + i * 256;
        float4 v = pred[idx4];
        int x = (idx4 << 2) & 1023;
        int y = (idx4 >> 8) & 1023;
        bool m0 = v.x > 0.5f, m1 = v.y > 0.5f, m2 = v.z > 0.5f, m3 = v.w > 0.5f;
        int cmn = m0 ? x : (m1 ? x + 1 : (m2 ? x + 2 : (m3 ? x + 3 : BIGI)));
        int cmx = m3 ? x + 3 : (m2 ? x + 2 : (m1 ? x + 1 : (m0 ? x : -1)));
        xmn = min(xmn, cmn);
        xmx = max(xmx, cmx);
        if (m0 | m1 | m2 | m3) { ymn = min(ymn, y); ymx = max(ymx, y); }
    }
    for (int off = 32; off > 0; off >>= 1) {
        xmn = min(xmn, __shfl_down(xmn, off));
        xmx = max(xmx, __shfl_down(xmx, off));
        ymn = min(ymn, __shfl_down(ymn, off));
        ymx = max(ymx, __shfl_down(ymx, off));
    }
    __shared__ int red[4][4];
    int wave = tid >> 6;
    if ((tid & 63) == 0) { red[0][wave] = xmn; red[1][wave] = xmx; red[2][wave] = ymn; red[3][wave] = ymx; }
    __syncthreads();
    if (tid == 0) {
        xmn = min(min(red[0][0], red[0][1]), min(red[0][2], red[0][3]));
        xmx = max(max(red[1][0], red[1][1]), max(red[1][2], red[1][3]));
        ymn = min(min(red[2][0], red[2][1]), min(red[2][2], red[2][3]));
        ymx = max(max(red[3][0], red[3][1]), max(red[3][2], red[3][3]));
        ((int4*)(ws + PM_OFF))[blockIdx.x] = make_int4(xmn, xmx, ymn, ymx);
    }
}

__device__ __forceinline__ void mk_bbox(int xmn, int xmx, int ymn, int ymx, float* o) {
    if (xmx >= 0) {
        o[0] = (float)(xmn + xmx) * (0.5f / 1024.0f);
        o[1] = (float)(ymn + ymx) * (0.5f / 1024.0f);
        o[2] = (float)(xmx - xmn) * (1.0f / 1024.0f);
        o[3] = (float)(ymx - ymn) * (1.0f / 1024.0f);
    } else { o[0] = 0.5f; o[1] = 0.5f; o[2] = 0.1f; o[3] = 0.1f; }
}

// ---------------- kernel 2: 3-stage pipelined LSTM + heads ----------------
// 96 WGs x 256 threads, __launch_bounds__(256,1) -- the PROVEN residency shape
// (rounds 3/4: VGPR=236). stage = blk>>5 (0:L0 whh0, 1:L1xg wih1, 2:L1rec whh1);
// b = (blk>>3)&3, g = blk&7. WG owns 128 gate-cols: j = tid&127, kh = tid>>7,
// col = (j>>5)*256 + g*32 + (j&31); thread slice = 128 rows x 1 col = ONE
// wreg[32] float4 array (128 VGPRs), reused wih0->whh0 in L0 (round-3 pattern).
__global__ __launch_bounds__(256, 1) void k_fused(
    const float* __restrict__ pe_w1, const float* __restrict__ pe_b1,
    const float* __restrict__ pe_w2, const float* __restrict__ pe_b2,
    const float* __restrict__ wih0, const float* __restrict__ whh0,
    const float* __restrict__ bih0, const float* __restrict__ bhh0,
    const float* __restrict__ wih1, const float* __restrict__ whh1,
    const float* __restrict__ bih1, const float* __restrict__ bhh1,
    const float* __restrict__ mp_w1, const float* __restrict__ mp_b1,
    const float* __restrict__ mp_w2, const float* __restrict__ mp_b2,
    const float* __restrict__ mp_w3, const float* __restrict__ mp_b3,
    const float* __restrict__ cf_w1, const float* __restrict__ cf_b1,
    const float* __restrict__ cf_w2, const float* __restrict__ cf_b2,
    const int4* __restrict__ pm4, unsigned long long* __restrict__ hT0,
    unsigned long long* __restrict__ hT2, unsigned long long* __restrict__ xg1,
    float* __restrict__ out) {
    __shared__ __align__(16) float sA[4096];  // L0: pos2; L1rec g0: heads scratch
    __shared__ __align__(16) float sB[4096];  // L0: p1, then xg0 kh-partials
    __shared__ float xgl[2048];               // L0: xg0[t][j] (biases folded)
    __shared__ __align__(16) float hsm[256];  // polled h (h1 or h2)
    __shared__ float xsm[128];                // L1rec: polled xg1[t] (own cols)
    __shared__ float part[256];
    __shared__ float sBB[64];
    const int tid = threadIdx.x, blk = blockIdx.x;
    const int stage = blk >> 5;
    const int b = (blk >> 3) & 3, g = blk & 7;
    const int j = tid & 127, kh = tid >> 7;
    const int col = ((j >> 5) << 8) + g * 32 + (j & 31);
    const int krow0 = kh * 128;

    float4 wreg[32];
    float cst = 0.0f;

    if (stage == 0) {
        // ======================= L0 =======================
        {   // bbox for this batch's 16 images: thread = (il = tid>>4, pair c2)
            int il = tid >> 4, c2 = (tid & 15) * 2;
            int4 A = pm4[(b * 16 + il) * 32 + c2];
            int4 B = pm4[(b * 16 + il) * 32 + c2 + 1];
            int xmn = min(A.x, B.x), xmx = max(A.y, B.y);
            int ymn = min(A.z, B.z), ymx = max(A.w, B.w);
            for (int off = 8; off > 0; off >>= 1) {
                xmn = min(xmn, __shfl_down(xmn, off, 16));
                xmx = max(xmx, __shfl_down(xmx, off, 16));
                ymn = min(ymn, __shfl_down(ymn, off, 16));
                ymx = max(ymx, __shfl_down(ymx, off, 16));
            }
            if ((tid & 15) == 0) {
                float bb[4];
                mk_bbox(xmn, xmx, ymn, ymx, bb);
                sBB[il * 4 + 0] = bb[0]; sBB[il * 4 + 1] = bb[1];
                sBB[il * 4 + 2] = bb[2]; sBB[il * 4 + 3] = bb[3];
                if (g == 0) {
                    out[OUT_BBOX + (b * 16 + il) * 4 + 0] = bb[0];
                    out[OUT_BBOX + (b * 16 + il) * 4 + 1] = bb[1];
                    out[OUT_BBOX + (b * 16 + il) * 4 + 2] = bb[2];
                    out[OUT_BBOX + (b * 16 + il) * 4 + 3] = bb[3];
                }
            }
        }
        __syncthreads();
        {   // p1[i][tid], 16 rows
            float w0 = pe_w1[tid], w1 = pe_w1[256 + tid];
            float w2 = pe_w1[512 + tid], w3 = pe_w1[768 + tid], b1v = pe_b1[tid];
#pragma unroll
            for (int i = 0; i < 16; ++i) {
                float v = sBB[i * 4] * w0 + sBB[i * 4 + 1] * w1 +
                          sBB[i * 4 + 2] * w2 + sBB[i * 4 + 3] * w3 + b1v;
                sB[i * 256 + tid] = fmaxf(v, 0.0f);
            }
        }
        __syncthreads();
        {   // pos2[i][tid], 16 rows
            float acc[16];
            float b2v = pe_b2[tid];
#pragma unroll
            for (int i = 0; i < 16; ++i) acc[i] = b2v;
            for (int k = 0; k < 256; ++k) {
                float wv = pe_w2[k * 256 + tid];
#pragma unroll
                for (int i = 0; i < 16; ++i) acc[i] += sB[i * 256 + k] * wv;
            }
#pragma unroll
            for (int i = 0; i < 16; ++i) sA[i * 256 + tid] = fmaxf(acc[i], 0.0f);
        }
        __syncthreads();
#pragma unroll
        for (int k4 = 0; k4 < 32; ++k4) {  // wih0 slice (transient, same array)
            int r = krow0 + k4 * 4;
            wreg[k4].x = wih0[(r + 0) * 1024 + col];
            wreg[k4].y = wih0[(r + 1) * 1024 + col];
            wreg[k4].z = wih0[(r + 2) * 1024 + col];
            wreg[k4].w = wih0[(r + 3) * 1024 + col];
        }
        {
            float xacc[16];
#pragma unroll
            for (int t = 0; t < 16; ++t) {
                const float4* pr = (const float4*)&sA[t * 256 + krow0];
                float a = 0.0f;
#pragma unroll
                for (int k = 0; k < 32; ++k) {
                    float4 x = pr[k];
                    a += x.x * wreg[k].x + x.y * wreg[k].y + x.z * wreg[k].z + x.w * wreg[k].w;
                }
                xacc[t] = a;
            }
#pragma unroll
            for (int t = 0; t < 16; ++t) sB[kh * 2048 + t * 128 + j] = xacc[t];
        }
        __syncthreads();
        {   // combine kh-halves + fold both biases; (j2, th) handles 8 t's
            float bsum = bih0[col] + bhh0[col];
            int th = tid >> 7;
            for (int i = 0; i < 8; ++i) {
                int t = th + 2 * i;
                xgl[t * 128 + j] = sB[t * 128 + j] + sB[2048 + t * 128 + j] + bsum;
            }
        }
#pragma unroll
        for (int k4 = 0; k4 < 32; ++k4) {  // whh0 slice (resident for t-loop)
            int r = krow0 + k4 * 4;
            wreg[k4].x = whh0[(r + 0) * 1024 + col];
            wreg[k4].y = whh0[(r + 1) * 1024 + col];
            wreg[k4].z = whh0[(r + 2) * 1024 + col];
            wreg[k4].w = whh0[(r + 3) * 1024 + col];
        }
        __syncthreads();
        for (int t = 0; t < 16; ++t) {
            if (t) hsm[tid] = pollh(&hT0[((b * 16 + t - 1) << 8) + tid], t);
            __syncthreads();
            float a = 0.0f;
            if (t) {
                const float4* hr = (const float4*)&hsm[krow0];
#pragma unroll
                for (int k = 0; k < 32; ++k) {
                    float4 h = hr[k];
                    a += h.x * wreg[k].x + h.y * wreg[k].y + h.z * wreg[k].z + h.w * wreg[k].w;
                }
            }
            part[tid] = a;
            __syncthreads();
            if (tid < 32) {
                int u = tid;
                float gi = xgl[t * 128 + u]      + part[u]       + part[128 + u];
                float gf = xgl[t * 128 + 32 + u] + part[32 + u]  + part[160 + u];
                float gg = xgl[t * 128 + 64 + u] + part[64 + u]  + part[192 + u];
                float go = xgl[t * 128 + 96 + u] + part[96 + u]  + part[224 + u];
                float i_ = sigmoidf_(gi), f_ = sigmoidf_(gf);
                float g_ = tanhf(gg), o_ = sigmoidf_(go);
                cst = f_ * cst + i_ * g_;
                float h = o_ * tanhf(cst);
                storeh(&hT0[((b * 16 + t) << 8) + g * 32 + u], h, t + 1);
            }
        }
        return;
    }

    if (stage == 1) {
        // ======================= L1xg =======================
#pragma unroll
        for (int k4 = 0; k4 < 32; ++k4) {  // wih1 slice (resident)
            int r = krow0 + k4 * 4;
            wreg[k4].x = wih1[(r + 0) * 1024 + col];
            wreg[k4].y = wih1[(r + 1) * 1024 + col];
            wreg[k4].z = wih1[(r + 2) * 1024 + col];
            wreg[k4].w = wih1[(r + 3) * 1024 + col];
        }
        float bsum = (tid < 128) ? (bih1[col] + bhh1[col]) : 0.0f;
        for (int t = 0; t < 16; ++t) {
            hsm[tid] = pollh(&hT0[((b * 16 + t) << 8) + tid], t + 1);
            __syncthreads();
            const float4* hr = (const float4*)&hsm[krow0];
            float a = 0.0f;
#pragma unroll
            for (int k = 0; k < 32; ++k) {
                float4 h = hr[k];
                a += h.x * wreg[k].x + h.y * wreg[k].y + h.z * wreg[k].z + h.w * wreg[k].w;
            }
            part[tid] = a;
            __syncthreads();
            if (tid < 128)
                storeh(&xg1[((b * 16 + t) << 10) + col], part[tid] + part[128 + tid] + bsum, t + 1);
        }
        return;
    }

    // ======================= L1rec (+ heads on g==0) =======================
#pragma unroll
    for (int k4 = 0; k4 < 32; ++k4) {  // whh1 slice (resident)
        int r = krow0 + k4 * 4;
        wreg[k4].x = whh1[(r + 0) * 1024 + col];
        wreg[k4].y = whh1[(r + 1) * 1024 + col];
        wreg[k4].z = whh1[(r + 2) * 1024 + col];
        wreg[k4].w = whh1[(r + 3) * 1024 + col];
    }
    for (int t = 0; t < 16; ++t) {
        if (tid < 128) {  // dual poll: xg1[t][own col] + h2[t-1][unit tid]
            if (t) {
                float2 v = pollh2(&xg1[((b * 16 + t) << 10) + col], t + 1,
                                  &hT2[(((b << 1) | ((t - 1) & 1)) << 8) + tid], t);
                xsm[tid] = v.x; hsm[tid] = v.y;
            } else {
                xsm[tid] = pollh(&xg1[((b * 16) << 10) + col], 1);
            }
        } else if (t) {
            hsm[tid] = pollh(&hT2[(((b << 1) | ((t - 1) & 1)) << 8) + tid], t);
        }
        __syncthreads();
        float a = 0.0f;
        if (t) {
            const float4* hr = (const float4*)&hsm[krow0];
#pragma unroll
            for (int k = 0; k < 32; ++k) {
                float4 h = hr[k];
                a += h.x * wreg[k].x + h.y * wreg[k].y + h.z * wreg[k].z + h.w * wreg[k].w;
            }
        }
        part[tid] = a;
        __syncthreads();
        if (tid < 32) {
            int u = tid, unit = g * 32 + u;
            float gi = xsm[u]      + part[u]       + part[128 + u];
            float gf = xsm[32 + u] + part[32 + u]  + part[160 + u];
            float gg = xsm[64 + u] + part[64 + u]  + part[192 + u];
            float go = xsm[96 + u] + part[96 + u]  + part[224 + u];
            float i_ = sigmoidf_(gi), f_ = sigmoidf_(gf);
            float g_ = tanhf(gg), o_ = sigmoidf_(go);
            cst = f_ * cst + i_ * g_;
            float h = o_ * tanhf(cst);
            storeh(&hT2[(((b << 1) | (t & 1)) << 8) + unit], h, t + 1);
            out[OUT_MF + (b * 16 + t) * 256 + unit] = h;
        }
    }
    if (g != 0) return;

    // ---- heads (one WG per batch) ----
    float* lh = sA;          // 256
    float* x1 = sA + 256;    // 256
    float* c1 = sA + 512;    // 128
    float* x2 = sA + 640;    // 128
    float* dl = sA + 768;    // 20
    lh[tid] = pollh(&hT2[(((b << 1) | 1) << 8) + tid], 16);
    if (tid < 32) {  // bbox of image b*16+15 for cumsum base
        int4 v = pm4[(b * 16 + 15) * 32 + tid];
        int xmn = v.x, xmx = v.y, ymn = v.z, ymx = v.w;
        for (int off = 16; off > 0; off >>= 1) {
            xmn = min(xmn, __shfl_down(xmn, off, 32));
            xmx = max(xmx, __shfl_down(xmx, off, 32));
            ymn = min(ymn, __shfl_down(ymn, off, 32));
            ymx = max(ymx, __shfl_down(ymx, off, 32));
        }
        if (tid == 0) mk_bbox(xmn, xmx, ymn, ymx, sBB);
    }
    __syncthreads();
    {   // x1 = relu(lh @ mp_w1 + mp_b1)
        float a = mp_b1[tid];
#pragma unroll 4
        for (int k = 0; k < 256; ++k) a += lh[k] * mp_w1[k * 256 + tid];
        x1[tid] = fmaxf(a, 0.0f);
    }
    __syncthreads();
    if (tid < 128) {  // x2 = relu(x1 @ mp_w2 + mp_b2)
        float a = mp_b2[tid];
#pragma unroll 4
        for (int k = 0; k < 256; ++k) a += x1[k] * mp_w2[k * 128 + tid];
        x2[tid] = fmaxf(a, 0.0f);
    } else {          // c1 = relu(lh @ cf_w1 + cf_b1)
        int jj = tid - 128;
        float a = cf_b1[jj];
#pragma unroll 4
        for (int k = 0; k < 256; ++k) a += lh[k] * cf_w1[k * 128 + jj];
        c1[jj] = fmaxf(a, 0.0f);
    }
    __syncthreads();
    if (tid < 20) {  // deltas = x2 @ mp_w3 + mp_b3
        float a = mp_b3[tid];
#pragma unroll 4
        for (int k = 0; k < 128; ++k) a += x2[k] * mp_w3[k * 20 + tid];
        dl[tid] = a;
        out[OUT_DELTAS + b * 20 + tid] = a;
    } else if (tid >= 32 && tid < 37) {  // confidence = sigmoid(c1 @ cf_w2 + cf_b2)
        int idx = tid - 32;
        float a = cf_b2[idx];
#pragma unroll 4
        for (int k = 0; k < 128; ++k) a += c1[k] * cf_w2[k * 5 + idx];
        out[OUT_CONF + b * 5 + idx] = sigmoidf_(a);
    }
    __syncthreads();
    if (tid < 4) {  // cumsum of deltas onto last bbox
        float acc = sBB[tid];
        for (int hh = 0; hh < 5; ++hh) {
            acc += dl[hh * 4 + tid];
            out[OUT_PBB + b * 20 + hh * 4 + tid] = acc;
            if (tid < 2) out[OUT_LOC + b * 10 + hh * 2 + tid] = acc;
            else out[OUT_SCL + b * 10 + hh * 2 + (tid - 2)] = acc;
        }
    }
}

extern "C" void kernel_launch(void* const* d_in, const int* in_sizes, int n_in,
                              void* d_out, int out_size, void* d_ws, size_t ws_size,
                              hipStream_t stream) {
    (void)in_sizes; (void)n_in; (void)out_size; (void)ws_size;
    const float* pred = (const float*)d_in[1];  // d_in[0] = features (unused)
    const float* pe_w1 = (const float*)d_in[2];
    const float* pe_b1 = (const float*)d_in[3];
    const float* pe_w2 = (const float*)d_in[4];
    const float* pe_b2 = (const float*)d_in[5];
    const float* wih0 = (const float*)d_in[6];
    const float* whh0 = (const float*)d_in[7];
    const float* bih0 = (const float*)d_in[8];
    const float* bhh0 = (const float*)d_in[9];
    const float* wih1 = (const float*)d_in[10];
    const float* whh1 = (const float*)d_in[11];
    const float* bih1 = (const float*)d_in[12];
    const float* bhh1 = (const float*)d_in[13];
    const float* mp_w1 = (const float*)d_in[14];
    const float* mp_b1 = (const float*)d_in[15];
    const float* mp_w2 = (const float*)d_in[16];
    const float* mp_b2 = (const float*)d_in[17];
    const float* mp_w3 = (const float*)d_in[18];
    const float* mp_b3 = (const float*)d_in[19];
    const float* cf_w1 = (const float*)d_in[20];
    const float* cf_b1 = (const float*)d_in[21];
    const float* cf_w2 = (const float*)d_in[22];
    const float* cf_b2 = (const float*)d_in[23];
    float* out = (float*)d_out;
    int* wsi = (int*)d_ws;

    hipLaunchKernelGGL(k_minmax, dim3(64 * 32), dim3(256), 0, stream,
                       (const float4*)pred, wsi);
    hipLaunchKernelGGL(k_fused, dim3(96), dim3(256), 0, stream,
                       pe_w1, pe_b1, pe_w2, pe_b2,
                       wih0, whh0, bih0, bhh0,
                       wih1, whh1, bih1, bhh1,
                       mp_w1, mp_b1, mp_w2, mp_b2, mp_w3, mp_b3,
                       cf_w1, cf_b1, cf_w2, cf_b2,
                       (const int4*)(wsi + PM_OFF),
                       (unsigned long long*)(wsi + HT0_OFF),
                       (unsigned long long*)(wsi + HT2_OFF),
                       (unsigned long long*)(wsi + XG1_OFF),
                       out);
}

// Round 12
// 560.069 us; speedup vs baseline: 1.0177x; 1.0177x over previous
//
#include <hip/hip_runtime.h>
#include <math.h>

#define BIGI (1 << 30)

// ---- workspace layout (4-byte words), total 176128 words = 688 KB ----
#define PM_OFF    0         // 2048 x int4 minmax partials
#define HT0_OFF   8192      // 4 x 16 x 256 tagged u64 (h1 history)
#define HT2_OFF   40960     // 4 x 2 x 256 tagged u64 (h2 double buffer)
#define XG1_OFF   45056     // 4 x 16 x 1024 tagged u64 (xg1 per t)
#define ZERO_BEG  8192
#define ZERO_END  176128

// ---- output layout (floats) ----
#define OUT_DELTAS 0       // (4,5,4)
#define OUT_PBB    80      // (4,5,4)
#define OUT_LOC    160     // (4,5,2)
#define OUT_SCL    200     // (4,5,2)
#define OUT_MF     240     // (4,16,256)
#define OUT_CONF   16624   // (4,5)
#define OUT_BBOX   16644   // (4,16,4)

__device__ __forceinline__ float sigmoidf_(float x) { return 1.0f / (1.0f + expf(-x)); }

// ---- self-signaling exchange: one 8B atomic payload = (tag<<32)|float ----
__device__ __forceinline__ void storeh(unsigned long long* p, float h, int tag) {
    unsigned long long v =
        ((unsigned long long)(unsigned)tag << 32) | (unsigned long long)__float_as_uint(h);
    __hip_atomic_store(p, v, __ATOMIC_RELAXED, __HIP_MEMORY_SCOPE_AGENT);
}
__device__ __forceinline__ float pollh(const unsigned long long* p, int tag) {
    unsigned long long v = __hip_atomic_load(p, __ATOMIC_RELAXED, __HIP_MEMORY_SCOPE_AGENT);
    while ((int)(v >> 32) != tag) {
        __builtin_amdgcn_s_sleep(1);
        v = __hip_atomic_load(p, __ATOMIC_RELAXED, __HIP_MEMORY_SCOPE_AGENT);
    }
    return __uint_as_float((unsigned)v);
}

// ---------------- kernel 1: minmax partials + zero tag region ----------------
__global__ __launch_bounds__(256) void k_minmax(const float4* __restrict__ pred,
                                                int* __restrict__ ws) {
    int tid = threadIdx.x;
    {   // zero tagged regions (blocks cover the range in one pass)
        int i = ZERO_BEG + blockIdx.x * 256 + tid;
        if (i < ZERO_END) ws[i] = 0;
    }
    int img = blockIdx.x >> 5;
    int chunk = blockIdx.x & 31;
    int base = img * 262144 + chunk * 8192 + tid;
    int xmn = BIGI, xmx = -1, ymn = BIGI, ymx = -1;
#pragma unroll 4
    for (int i = 0; i < 32; ++i) {
        int idx4 = base + i * 256;
        float4 v = pred[idx4];
        int x = (idx4 << 2) & 1023;
        int y = (idx4 >> 8) & 1023;
        bool m0 = v.x > 0.5f, m1 = v.y > 0.5f, m2 = v.z > 0.5f, m3 = v.w > 0.5f;
        int cmn = m0 ? x : (m1 ? x + 1 : (m2 ? x + 2 : (m3 ? x + 3 : BIGI)));
        int cmx = m3 ? x + 3 : (m2 ? x + 2 : (m1 ? x + 1 : (m0 ? x : -1)));
        xmn = min(xmn, cmn);
        xmx = max(xmx, cmx);
        if (m0 | m1 | m2 | m3) { ymn = min(ymn, y); ymx = max(ymx, y); }
    }
    for (int off = 32; off > 0; off >>= 1) {
        xmn = min(xmn, __shfl_down(xmn, off));
        xmx = max(xmx, __shfl_down(xmx, off));
        ymn = min(ymn, __shfl_down(ymn, off));
        ymx = max(ymx, __shfl_down(ymx, off));
    }
    __shared__ int red[4][4];
    int wave = tid >> 6;
    if ((tid & 63) == 0) { red[0][wave] = xmn; red[1][wave] = xmx; red[2][wave] = ymn; red[3][wave] = ymx; }
    __syncthreads();
    if (tid == 0) {
        xmn = min(min(red[0][0], red[0][1]), min(red[0][2], red[0][3]));
        xmx = max(max(red[1][0], red[1][1]), max(red[1][2], red[1][3]));
        ymn = min(min(red[2][0], red[2][1]), min(red[2][2], red[2][3]));
        ymx = max(max(red[3][0], red[3][1]), max(red[3][2], red[3][3]));
        ((int4*)(ws + PM_OFF))[blockIdx.x] = make_int4(xmn, xmx, ymn, ymx);
    }
}

__device__ __forceinline__ void mk_bbox(int xmn, int xmx, int ymn, int ymx, float* o) {
    if (xmx >= 0) {
        o[0] = (float)(xmn + xmx) * (0.5f / 1024.0f);
        o[1] = (float)(ymn + ymx) * (0.5f / 1024.0f);
        o[2] = (float)(xmx - xmn) * (1.0f / 1024.0f);
        o[3] = (float)(ymx - ymn) * (1.0f / 1024.0f);
    } else { o[0] = 0.5f; o[1] = 0.5f; o[2] = 0.1f; o[3] = 0.1f; }
}

// ---------------- kernel 2: 3-stage pipelined LSTM + heads ----------------
// 48 WGs x 512 threads (R7 configuration -- session-best measured: 559.0 us).
// blk>>4 = stage (0:L0rec whh0, 1:L1xg wih1, 2:L1rec whh1); b=(blk>>2)&3,
// g=blk&3. Each WG owns 256 gate-cols: c=tid&255, kh=tid>>8,
// col = (c>>6)*256 + g*64 + (c&63); thread holds 128 rows x 1 col = wreg[32].
// Cross-WG exchange: self-signaling tagged 8B payloads + s_sleep polls.
__global__ __launch_bounds__(512, 2) void k_fused(
    const float* __restrict__ pe_w1, const float* __restrict__ pe_b1,
    const float* __restrict__ pe_w2, const float* __restrict__ pe_b2,
    const float* __restrict__ wih0, const float* __restrict__ whh0,
    const float* __restrict__ bih0, const float* __restrict__ bhh0,
    const float* __restrict__ wih1, const float* __restrict__ whh1,
    const float* __restrict__ bih1, const float* __restrict__ bhh1,
    const float* __restrict__ mp_w1, const float* __restrict__ mp_b1,
    const float* __restrict__ mp_w2, const float* __restrict__ mp_b2,
    const float* __restrict__ mp_w3, const float* __restrict__ mp_b3,
    const float* __restrict__ cf_w1, const float* __restrict__ cf_b1,
    const float* __restrict__ cf_w2, const float* __restrict__ cf_b2,
    const int4* __restrict__ pm4, unsigned long long* __restrict__ hT0,
    unsigned long long* __restrict__ hT2, unsigned long long* __restrict__ xg1,
    float* __restrict__ out) {
    __shared__ __align__(16) float sA[4096];  // L0rec: pos2; L1rec g0: heads scratch
    __shared__ __align__(16) float sB[4096];  // L0rec: p1 then xg0[t][c]
    __shared__ __align__(16) float hsm[256];  // polled h (h1 or h2)
    __shared__ float xsm[256];                // L1rec: polled xg1[t]
    __shared__ float partA[512];
    __shared__ float sBB[64];
    const int tid = threadIdx.x, blk = blockIdx.x;
    const int stage = blk >> 4;
    const int b = (blk >> 2) & 3, g = blk & 3;
    const int c = tid & 255, kh = tid >> 8;
    const int col = ((c >> 6) << 8) + g * 64 + (c & 63);
    const int krow0 = kh * 128;

    float4 wreg[32];
    float cst = 0.0f;

    if (stage == 0) {
        // ======================= L0rec =======================
        {   // bbox for 16 images: thread = (il = tid>>5, ch = tid&31)
            int il = tid >> 5, ch = tid & 31;
            int4 v = pm4[(b * 16 + il) * 32 + ch];
            int xmn = v.x, xmx = v.y, ymn = v.z, ymx = v.w;
            for (int off = 16; off > 0; off >>= 1) {
                xmn = min(xmn, __shfl_down(xmn, off, 32));
                xmx = max(xmx, __shfl_down(xmx, off, 32));
                ymn = min(ymn, __shfl_down(ymn, off, 32));
                ymx = max(ymx, __shfl_down(ymx, off, 32));
            }
            if (ch == 0) {
                float bb[4];
                mk_bbox(xmn, xmx, ymn, ymx, bb);
                sBB[il * 4 + 0] = bb[0]; sBB[il * 4 + 1] = bb[1];
                sBB[il * 4 + 2] = bb[2]; sBB[il * 4 + 3] = bb[3];
                if (g == 0) {
                    out[OUT_BBOX + (b * 16 + il) * 4 + 0] = bb[0];
                    out[OUT_BBOX + (b * 16 + il) * 4 + 1] = bb[1];
                    out[OUT_BBOX + (b * 16 + il) * 4 + 2] = bb[2];
                    out[OUT_BBOX + (b * 16 + il) * 4 + 3] = bb[3];
                }
            }
        }
        __syncthreads();
        if (tid < 256) {  // p1[i][tid], 16 rows
            float w0 = pe_w1[tid], w1 = pe_w1[256 + tid];
            float w2 = pe_w1[512 + tid], w3 = pe_w1[768 + tid], b1v = pe_b1[tid];
#pragma unroll
            for (int i = 0; i < 16; ++i) {
                float v = sBB[i * 4] * w0 + sBB[i * 4 + 1] * w1 +
                          sBB[i * 4 + 2] * w2 + sBB[i * 4 + 3] * w3 + b1v;
                sB[i * 256 + tid] = fmaxf(v, 0.0f);
            }
        }
        __syncthreads();
        {   // pos2: thread (c, kh) -> rows kh*8..kh*8+8
            int i0 = kh * 8;
            float acc[8];
            float b2v = pe_b2[c];
#pragma unroll
            for (int i = 0; i < 8; ++i) acc[i] = b2v;
            for (int k = 0; k < 256; ++k) {
                float wv = pe_w2[k * 256 + c];
#pragma unroll
                for (int i = 0; i < 8; ++i) acc[i] += sB[(i0 + i) * 256 + k] * wv;
            }
#pragma unroll
            for (int i = 0; i < 8; ++i) sA[(i0 + i) * 256 + c] = fmaxf(acc[i], 0.0f);
        }
        __syncthreads();
#pragma unroll
        for (int k4 = 0; k4 < 32; ++k4) {  // wih0 slice (transient)
            int r = krow0 + k4 * 4;
            wreg[k4].x = wih0[(r + 0) * 1024 + col];
            wreg[k4].y = wih0[(r + 1) * 1024 + col];
            wreg[k4].z = wih0[(r + 2) * 1024 + col];
            wreg[k4].w = wih0[(r + 3) * 1024 + col];
        }
        float xacc[16];
#pragma unroll
        for (int t = 0; t < 16; ++t) {  // xg0 partials, all t
            const float4* pr = (const float4*)&sA[t * 256 + krow0];
            float a = 0.0f;
#pragma unroll
            for (int k = 0; k < 32; ++k) {
                float4 x = pr[k];
                a += x.x * wreg[k].x + x.y * wreg[k].y + x.z * wreg[k].z + x.w * wreg[k].w;
            }
            xacc[t] = a;
        }
        if (kh == 1) {
#pragma unroll
            for (int t = 0; t < 16; ++t) sB[t * 256 + c] = xacc[t];
        }
        __syncthreads();
        if (kh == 0) {
            float bsum = bih0[col] + bhh0[col];
#pragma unroll
            for (int t = 0; t < 16; ++t) sB[t * 256 + c] = xacc[t] + sB[t * 256 + c] + bsum;
        }
        __syncthreads();
#pragma unroll
        for (int k4 = 0; k4 < 32; ++k4) {  // whh0 slice (resident for t-loop)
            int r = krow0 + k4 * 4;
            wreg[k4].x = whh0[(r + 0) * 1024 + col];
            wreg[k4].y = whh0[(r + 1) * 1024 + col];
            wreg[k4].z = whh0[(r + 2) * 1024 + col];
            wreg[k4].w = whh0[(r + 3) * 1024 + col];
        }
        for (int t = 0; t < 16; ++t) {
            if (t && tid < 256) hsm[tid] = pollh(&hT0[((b * 16 + t - 1) << 8) + tid], t);
            __syncthreads();
            float a = 0.0f;
            if (t) {
                const float4* hr = (const float4*)&hsm[krow0];
#pragma unroll
                for (int k = 0; k < 32; ++k) {
                    float4 h = hr[k];
                    a += h.x * wreg[k].x + h.y * wreg[k].y + h.z * wreg[k].z + h.w * wreg[k].w;
                }
            }
            partA[kh * 256 + c] = a;
            __syncthreads();
            if (tid < 64) {
                int u = tid, unit = g * 64 + u;
                float gi = sB[t * 256 + u]       + partA[u]       + partA[256 + u];
                float gf = sB[t * 256 + 64 + u]  + partA[64 + u]  + partA[320 + u];
                float gg = sB[t * 256 + 128 + u] + partA[128 + u] + partA[384 + u];
                float go = sB[t * 256 + 192 + u] + partA[192 + u] + partA[448 + u];
                float i_ = sigmoidf_(gi), f_ = sigmoidf_(gf);
                float g_ = tanhf(gg), o_ = sigmoidf_(go);
                cst = f_ * cst + i_ * g_;
                float h = o_ * tanhf(cst);
                storeh(&hT0[((b * 16 + t) << 8) + unit], h, t + 1);
            }
        }
        return;
    }

    if (stage == 1) {
        // ======================= L1xg =======================
#pragma unroll
        for (int k4 = 0; k4 < 32; ++k4) {  // wih1 slice (resident)
            int r = krow0 + k4 * 4;
            wreg[k4].x = wih1[(r + 0) * 1024 + col];
            wreg[k4].y = wih1[(r + 1) * 1024 + col];
            wreg[k4].z = wih1[(r + 2) * 1024 + col];
            wreg[k4].w = wih1[(r + 3) * 1024 + col];
        }
        float bsum = 0.0f;
        if (tid < 256) bsum = bih1[col] + bhh1[col];
        for (int t = 0; t < 16; ++t) {
            if (tid < 256) hsm[tid] = pollh(&hT0[((b * 16 + t) << 8) + tid], t + 1);
            __syncthreads();
            const float4* hr = (const float4*)&hsm[krow0];
            float a = 0.0f;
#pragma unroll
            for (int k = 0; k < 32; ++k) {
                float4 h = hr[k];
                a += h.x * wreg[k].x + h.y * wreg[k].y + h.z * wreg[k].z + h.w * wreg[k].w;
            }
            partA[kh * 256 + c] = a;
            __syncthreads();
            if (tid < 256) {
                float v = partA[tid] + partA[256 + tid] + bsum;
                storeh(&xg1[((b * 16 + t) << 10) + col], v, t + 1);
            }
        }
        return;
    }

    // ======================= L1rec (+ heads on g==0) =======================
#pragma unroll
    for (int k4 = 0; k4 < 32; ++k4) {  // whh1 slice (resident)
        int r = krow0 + k4 * 4;
        wreg[k4].x = whh1[(r + 0) * 1024 + col];
        wreg[k4].y = whh1[(r + 1) * 1024 + col];
        wreg[k4].z = whh1[(r + 2) * 1024 + col];
        wreg[k4].w = whh1[(r + 3) * 1024 + col];
    }
    for (int t = 0; t < 16; ++t) {
        if (tid < 256) {  // poll h2[t-1]
            if (t) hsm[tid] = pollh(&hT2[(((b << 1) | ((t - 1) & 1)) << 8) + tid], t);
        } else {          // poll xg1[t] (its own col slice), concurrently
            int cc = tid - 256;
            int colx = ((cc >> 6) << 8) + g * 64 + (cc & 63);
            xsm[cc] = pollh(&xg1[((b * 16 + t) << 10) + colx], t + 1);
        }
        __syncthreads();
        float a = 0.0f;
        if (t) {
            const float4* hr = (const float4*)&hsm[krow0];
#pragma unroll
            for (int k = 0; k < 32; ++k) {
                float4 h = hr[k];
                a += h.x * wreg[k].x + h.y * wreg[k].y + h.z * wreg[k].z + h.w * wreg[k].w;
            }
        }
        partA[kh * 256 + c] = a;
        __syncthreads();
        if (tid < 64) {
            int u = tid, unit = g * 64 + u;
            float gi = xsm[u]       + partA[u]       + partA[256 + u];
            float gf = xsm[64 + u]  + partA[64 + u]  + partA[320 + u];
            float gg = xsm[128 + u] + partA[128 + u] + partA[384 + u];
            float go = xsm[192 + u] + partA[192 + u] + partA[448 + u];
            float i_ = sigmoidf_(gi), f_ = sigmoidf_(gf);
            float g_ = tanhf(gg), o_ = sigmoidf_(go);
            cst = f_ * cst + i_ * g_;
            float h = o_ * tanhf(cst);
            storeh(&hT2[(((b << 1) | (t & 1)) << 8) + unit], h, t + 1);
            out[OUT_MF + (b * 16 + t) * 256 + unit] = h;
        }
    }
    if (g != 0) return;

    // ---- heads (one WG per batch) ----
    float* lh = sA;          // 256
    float* x1 = sA + 256;    // 256
    float* c1 = sA + 512;    // 128
    float* x2 = sA + 640;    // 128
    float* dl = sA + 768;    // 20
    if (tid < 256) lh[tid] = pollh(&hT2[(((b << 1) | 1) << 8) + tid], 16);
    if (tid < 32) {  // bbox of image b*16+15
        int4 v = pm4[(b * 16 + 15) * 32 + tid];
        int xmn = v.x, xmx = v.y, ymn = v.z, ymx = v.w;
        for (int off = 16; off > 0; off >>= 1) {
            xmn = min(xmn, __shfl_down(xmn, off, 32));
            xmx = max(xmx, __shfl_down(xmx, off, 32));
            ymn = min(ymn, __shfl_down(ymn, off, 32));
            ymx = max(ymx, __shfl_down(ymx, off, 32));
        }
        if (tid == 0) mk_bbox(xmn, xmx, ymn, ymx, sBB);
    }
    __syncthreads();
    if (tid < 256) {
        float a = mp_b1[tid];
#pragma unroll 4
        for (int k = 0; k < 256; ++k) a += lh[k] * mp_w1[k * 256 + tid];
        x1[tid] = fmaxf(a, 0.0f);
    } else if (tid < 384) {
        int jj = tid - 256;
        float a = cf_b1[jj];
#pragma unroll 4
        for (int k = 0; k < 256; ++k) a += lh[k] * cf_w1[k * 128 + jj];
        c1[jj] = fmaxf(a, 0.0f);
    }
    __syncthreads();
    if (tid < 128) {
        float a = mp_b2[tid];
#pragma unroll 4
        for (int k = 0; k < 256; ++k) a += x1[k] * mp_w2[k * 128 + tid];
        x2[tid] = fmaxf(a, 0.0f);
    } else if (tid >= 256 && tid < 261) {
        int jj = tid - 256;
        float a = cf_b2[jj];
#pragma unroll 4
        for (int k = 0; k < 128; ++k) a += c1[k] * cf_w2[k * 5 + jj];
        out[OUT_CONF + b * 5 + jj] = sigmoidf_(a);
    }
    __syncthreads();
    if (tid < 20) {
        float a = mp_b3[tid];
#pragma unroll 4
        for (int k = 0; k < 128; ++k) a += x2[k] * mp_w3[k * 20 + tid];
        dl[tid] = a;
        out[OUT_DELTAS + b * 20 + tid] = a;
    }
    __syncthreads();
    if (tid < 4) {
        float acc = sBB[tid];
        for (int hh = 0; hh < 5; ++hh) {
            acc += dl[hh * 4 + tid];
            out[OUT_PBB + b * 20 + hh * 4 + tid] = acc;
            if (tid < 2) out[OUT_LOC + b * 10 + hh * 2 + tid] = acc;
            else out[OUT_SCL + b * 10 + hh * 2 + (tid - 2)] = acc;
        }
    }
}

extern "C" void kernel_launch(void* const* d_in, const int* in_sizes, int n_in,
                              void* d_out, int out_size, void* d_ws, size_t ws_size,
                              hipStream_t stream) {
    (void)in_sizes; (void)n_in; (void)out_size; (void)ws_size;
    const float* pred = (const float*)d_in[1];  // d_in[0] = features (unused)
    const float* pe_w1 = (const float*)d_in[2];
    const float* pe_b1 = (const float*)d_in[3];
    const float* pe_w2 = (const float*)d_in[4];
    const float* pe_b2 = (const float*)d_in[5];
    const float* wih0 = (const float*)d_in[6];
    const float* whh0 = (const float*)d_in[7];
    const float* bih0 = (const float*)d_in[8];
    const float* bhh0 = (const float*)d_in[9];
    const float* wih1 = (const float*)d_in[10];
    const float* whh1 = (const float*)d_in[11];
    const float* bih1 = (const float*)d_in[12];
    const float* bhh1 = (const float*)d_in[13];
    const float* mp_w1 = (const float*)d_in[14];
    const float* mp_b1 = (const float*)d_in[15];
    const float* mp_w2 = (const float*)d_in[16];
    const float* mp_b2 = (const float*)d_in[17];
    const float* mp_w3 = (const float*)d_in[18];
    const float* mp_b3 = (const float*)d_in[19];
    const float* cf_w1 = (const float*)d_in[20];
    const float* cf_b1 = (const float*)d_in[21];
    const float* cf_w2 = (const float*)d_in[22];
    const float* cf_b2 = (const float*)d_in[23];
    float* out = (float*)d_out;
    int* wsi = (int*)d_ws;

    hipLaunchKernelGGL(k_minmax, dim3(64 * 32), dim3(256), 0, stream,
                       (const float4*)pred, wsi);
    hipLaunchKernelGGL(k_fused, dim3(48), dim3(512), 0, stream,
                       pe_w1, pe_b1, pe_w2, pe_b2,
                       wih0, whh0, bih0, bhh0,
                       wih1, whh1, bih1, bhh1,
                       mp_w1, mp_b1, mp_w2, mp_b2, mp_w3, mp_b3,
                       cf_w1, cf_b1, cf_w2, cf_b2,
                       (const int4*)(wsi + PM_OFF),
                       (unsigned long long*)(wsi + HT0_OFF),
                       (unsigned long long*)(wsi + HT2_OFF),
                       (unsigned long long*)(wsi + XG1_OFF),
                       out);
}